// Round 8
// baseline (524.220 us; speedup 1.0000x reference)
//
#include <hip/hip_runtime.h>

typedef unsigned short u16;
typedef unsigned int u32;

#define N_NODES 20000
#define NE 320000
#define NLAYERS 4
#define NCLASS 40
#define NEG_SLOPE 0.2f
#define LSTRIDE ((NLAYERS + 1) * 128)  // 640 floats per node in X_all/Y_all

typedef __bf16 bf16x8 __attribute__((ext_vector_type(8)));
typedef float f32x4 __attribute__((ext_vector_type(4)));

__device__ inline u16 f2bf(float f) {
    u32 u = __float_as_uint(f);
    return (u16)((u + 0x7fffu + ((u >> 16) & 1u)) >> 16);  // round-nearest-even
}
__device__ inline u32 pack2bf(float lo, float hi) {
    return (u32)f2bf(lo) | ((u32)f2bf(hi) << 16);
}

// ================= pre1: init + W-transpose + att-fold + degree-count (block-partitioned) ====
#define P1_INIT 10000
#define P1_TRANS 256
#define P1_FOLD 128
#define P1_COUNT 1250
__global__ __launch_bounds__(256) void k_pre1(
    const float* __restrict__ x, const int* __restrict__ dst,
    const float* __restrict__ W, const float* __restrict__ att_s,
    const float* __restrict__ att_d,
    u16* __restrict__ Xbf, float* __restrict__ Xall, float* __restrict__ Yall,
    u16* __restrict__ Wt, float* __restrict__ Vs, float* __restrict__ Vd,
    int* __restrict__ counts) {
    int b = blockIdx.x;
    if (b < P1_INIT) {
        int t = b * 256 + threadIdx.x;
        float v = x[t];
        Xbf[t] = f2bf(v);
        int n = t >> 7, c = t & 127;
        int ob = n * LSTRIDE + c;
        Xall[ob] = v;
        Yall[ob] = v;
    } else if (b < P1_INIT + P1_TRANS) {
        int t = (b - P1_INIT) * 256 + threadIdx.x;
        int k = t >> 9, col = t & 511;
        Wt[col * 128 + k] = f2bf(W[t]);
    } else if (b < P1_INIT + P1_TRANS + P1_FOLD) {
        int wid = ((b - P1_INIT - P1_TRANS) * 256 + threadIdx.x) >> 6;
        int lane = threadIdx.x & 63;
        int t = wid >> 2, hd = wid & 3;
        float w0 = W[t * 512 + hd * 128 + lane];
        float w1 = W[t * 512 + hd * 128 + 64 + lane];
        float s1 = w0 * att_s[hd * 128 + lane] + w1 * att_s[hd * 128 + 64 + lane];
        float s2 = w0 * att_d[hd * 128 + lane] + w1 * att_d[hd * 128 + 64 + lane];
        for (int off = 32; off; off >>= 1) {
            s1 += __shfl_xor(s1, off);
            s2 += __shfl_xor(s2, off);
        }
        if (lane == 0) {
            Vs[t * 4 + hd] = s1;
            Vd[t * 4 + hd] = s2;
        }
    } else {
        int t = (b - P1_INIT - P1_TRANS - P1_FOLD) * 256 + threadIdx.x;
        atomicAdd(&counts[dst[t]], 1);
    }
}

// ================= pre2: block 0 = CSR scan (+1 self loop); blocks 1.. = layer-0 logits ====
__global__ __launch_bounds__(1024) void k_pre2(
    const int* __restrict__ counts, int* __restrict__ indptr, int* __restrict__ cursor,
    const float* __restrict__ x, const float* __restrict__ Vs, const float* __restrict__ Vd,
    float* __restrict__ a_s, float* __restrict__ a_d) {
    if (blockIdx.x == 0) {
        __shared__ int part[1024];
        int t = threadIdx.x;
        const int CH = 20;
        int c0 = t * CH;
        int s = 0;
        for (int i = 0; i < CH; i++) {
            int idx = c0 + i;
            if (idx < N_NODES) s += counts[idx] + 1;
        }
        part[t] = s;
        __syncthreads();
        for (int off = 1; off < 1024; off <<= 1) {
            int v = 0;
            if (t >= off) v = part[t - off];
            __syncthreads();
            if (t >= off) part[t] += v;
            __syncthreads();
        }
        int ex = (t == 0) ? 0 : part[t - 1];
        for (int i = 0; i < CH; i++) {
            int idx = c0 + i;
            if (idx < N_NODES) {
                indptr[idx] = ex;
                cursor[idx] = ex;
                ex += counts[idx] + 1;
            }
        }
        if (t == 1023) indptr[N_NODES] = part[1023];
    } else {
        int wave = threadIdx.x >> 6, lane = threadIdx.x & 63;
        int n = (blockIdx.x - 1) * 16 + wave;
        const float* Xr = x + n * 128;
        float x0 = Xr[lane], x1 = Xr[64 + lane];
        f32x4 vs0 = *(const f32x4*)(Vs + lane * 4), vs1 = *(const f32x4*)(Vs + (64 + lane) * 4);
        f32x4 vd0 = *(const f32x4*)(Vd + lane * 4), vd1 = *(const f32x4*)(Vd + (64 + lane) * 4);
        f32x4 ps = x0 * vs0 + x1 * vs1;
        f32x4 pd = x0 * vd0 + x1 * vd1;
        for (int off = 32; off; off >>= 1)
            for (int c = 0; c < 4; c++) {
                ps[c] += __shfl_xor(ps[c], off);
                pd[c] += __shfl_xor(pd[c], off);
            }
        if (lane == 0) {
            *(f32x4*)(a_s + n * 4) = ps;
            *(f32x4*)(a_d + n * 4) = pd;
        }
    }
}

// ================= scatter: CSR fill (edges + self loops) ==================
__global__ void k_scatter(const int* __restrict__ src, const int* __restrict__ dst,
                          int* __restrict__ cursor, int* __restrict__ esrc) {
    int t = blockIdx.x * 256 + threadIdx.x;
    if (t >= NE + N_NODES) return;
    int s, d;
    if (t < NE) { s = src[t]; d = dst[t]; }
    else { s = d = t - NE; }
    int pos = atomicAdd(&cursor[d], 1);
    esrc[pos] = s;
}

// ================= fused layer (round-4 structure + LDS union + fused readout) =============
// block = 512 threads (8 waves), 16 nodes, grid 1250 exact.
// LDS: gather bufs (21.1KB, dead after As write) UNIONed with aggbuf (8.4KB) + As 16.6KB
//   = 37.8KB -> 4 blocks/CU at the compiler's NATURAL 64 VGPR.
// VGPR triangle is mapped: 108 (R6 depth-2) -> occupancy cliff, 2x slower; forced 32
// (R7 launch_bounds min-waves 8) -> spill, WRITE 104MB, 2x slower. Leave the allocator
// alone: no min-waves argument, depth-1 dual chain (R4-proven 64 VGPR).
__global__ __launch_bounds__(512) void k_layer(
    const int* __restrict__ indptr, const int* __restrict__ esrc,
    const float* __restrict__ a_s, const float* __restrict__ a_d,
    const u16* __restrict__ XbfR, const u16* __restrict__ Wt,
    const float* __restrict__ bias,
    float* __restrict__ Xall, float* __restrict__ Yall, u16* __restrict__ XbfW,
    float* __restrict__ a_s_nxt, float* __restrict__ a_d_nxt,
    const float* __restrict__ Vs, const float* __restrict__ Vd,
    const float* __restrict__ Wr, const float* __restrict__ br, float* __restrict__ outp,
    int layer, int mode) {
    __shared__ alignas(16) char smem[21120 + 16640];  // 37760 B
    int (*s_sh)[2][66] = (int(*)[2][66])smem;                      // [8][2][66]   4224 B
    float (*al_sh)[2][66][4] = (float(*)[2][66][4])(smem + 4224);  // [8][2][66][4] 16896 B
    float* aggbuf = (float*)smem;        // [16][132] f32 = 8448 B, aliases s_sh/al_sh (dead)
    u16* As = (u16*)(smem + 21120);      // [16][520] u16 = 16640 B
    const int t = threadIdx.x;
    const int r0 = blockIdx.x * 16;
    const int w = t >> 6, lane = t & 63;

    f32x4 acc00 = {0.f, 0.f, 0.f, 0.f}, acc01 = {0.f, 0.f, 0.f, 0.f};  // node0: ch 2l, 2l+1
    f32x4 acc10 = {0.f, 0.f, 0.f, 0.f}, acc11 = {0.f, 0.f, 0.f, 0.f};  // node1
    int d0 = r0 + w * 2;
    int st0 = indptr[d0], en0 = indptr[d0 + 1], en1 = indptr[d0 + 2];
    int st1 = en0;
    int deg0 = en0 - st0, deg1 = en1 - st1;
    f32x4 ad0 = *(const f32x4*)(a_d + d0 * 4);
    f32x4 ad1 = *(const f32x4*)(a_d + d0 * 4 + 4);

    // softmax for <=64-edge node: per-lane edge, alpha[4] -> per-wave LDS; slot 64 sentinel
    auto prep = [&](int nd, int st, int en, f32x4 ad) {
        int j = st + lane;
        int s = 0;
        f32x4 e = {-1e30f, -1e30f, -1e30f, -1e30f};
        if (j < en) {
            s = esrc[j];
            f32x4 as = *(const f32x4*)(a_s + s * 4);
            for (int cc = 0; cc < 4; cc++) {
                float v = as[cc] + ad[cc];
                e[cc] = v > 0.f ? v : NEG_SLOPE * v;
            }
        }
        f32x4 mx = e;
        for (int off = 32; off; off >>= 1)
            for (int cc = 0; cc < 4; cc++) mx[cc] = fmaxf(mx[cc], __shfl_xor(mx[cc], off));
        f32x4 p;
        for (int cc = 0; cc < 4; cc++) p[cc] = __expf(e[cc] - mx[cc]);  // invalid lanes -> 0
        f32x4 den = p;
        for (int off = 32; off; off >>= 1)
            for (int cc = 0; cc < 4; cc++) den[cc] += __shfl_xor(den[cc], off);
        f32x4 alpha;
        for (int cc = 0; cc < 4; cc++) alpha[cc] = p[cc] * (1.f / den[cc]);
        s_sh[w][nd][lane] = s;
        *(f32x4*)al_sh[w][nd][lane] = alpha;
        if (lane == 63) {  // sentinel for the deg==64 prefetch
            s_sh[w][nd][64] = 0;
            f32x4 z = {0.f, 0.f, 0.f, 0.f};
            *(f32x4*)al_sh[w][nd][64] = z;
        }
    };

    // general path (deg > 64): strided 3-pass softmax + chunked 1-deep aggregate (rare)
    auto chunk1 = [&](int nd, int cnt, f32x4& aL, f32x4& aH) {
        int sc = s_sh[w][nd][0];
        f32x4 al = *(const f32x4*)al_sh[w][nd][0];
        u32 xv = *(const u32*)(XbfR + sc * 128 + lane * 2);
        for (int i = 0; i < cnt; i++) {
            int sn = s_sh[w][nd][i + 1];
            f32x4 an = *(const f32x4*)al_sh[w][nd][i + 1];
            u32 xn = *(const u32*)(XbfR + sn * 128 + lane * 2);
            aL += al * __uint_as_float(xv << 16);
            aH += al * __uint_as_float(xv & 0xffff0000u);
            xv = xn; al = an;
        }
    };
    auto gen = [&](int nd, int st, int en, f32x4 ad, int row) {
        f32x4 accL = {0.f, 0.f, 0.f, 0.f}, accH = {0.f, 0.f, 0.f, 0.f};
        f32x4 mx = {-1e30f, -1e30f, -1e30f, -1e30f};
        for (int j = st + lane; j < en; j += 64) {
            int s = esrc[j];
            f32x4 e = *(const f32x4*)(a_s + s * 4) + ad;
            for (int cc = 0; cc < 4; cc++) {
                float v = e[cc];
                v = v > 0.f ? v : NEG_SLOPE * v;
                mx[cc] = fmaxf(mx[cc], v);
            }
        }
        for (int off = 32; off; off >>= 1)
            for (int cc = 0; cc < 4; cc++) mx[cc] = fmaxf(mx[cc], __shfl_xor(mx[cc], off));
        f32x4 den = {0.f, 0.f, 0.f, 0.f};
        for (int j = st + lane; j < en; j += 64) {
            int s = esrc[j];
            f32x4 e = *(const f32x4*)(a_s + s * 4) + ad;
            for (int cc = 0; cc < 4; cc++) {
                float v = e[cc];
                v = v > 0.f ? v : NEG_SLOPE * v;
                den[cc] += __expf(v - mx[cc]);
            }
        }
        for (int off = 32; off; off >>= 1)
            for (int cc = 0; cc < 4; cc++) den[cc] += __shfl_xor(den[cc], off);
        f32x4 rd;
        for (int cc = 0; cc < 4; cc++) rd[cc] = 1.f / den[cc];
        for (int base = st; base < en; base += 64) {
            int cnt = min(64, en - base);
            int jj = base + lane;
            int s = 0;
            f32x4 alpha = {0.f, 0.f, 0.f, 0.f};
            if (jj < en) {
                s = esrc[jj];
                f32x4 e = *(const f32x4*)(a_s + s * 4) + ad;
                for (int cc = 0; cc < 4; cc++) {
                    float v = e[cc];
                    v = v > 0.f ? v : NEG_SLOPE * v;
                    alpha[cc] = __expf(v - mx[cc]) * rd[cc];
                }
            }
            s_sh[w][nd][lane] = s;
            *(f32x4*)al_sh[w][nd][lane] = alpha;
            if (lane == 63) {
                s_sh[w][nd][64] = 0;
                f32x4 z = {0.f, 0.f, 0.f, 0.f};
                *(f32x4*)al_sh[w][nd][64] = z;
            }
            __builtin_amdgcn_wave_barrier();
            chunk1(nd, cnt, accL, accH);
            __builtin_amdgcn_wave_barrier();
        }
        u16* a0 = As + row * 520 + lane * 2;
        for (int h = 0; h < 4; h++)
            *(u32*)(a0 + h * 128) = pack2bf(accL[h], accH[h]);
    };

    if (deg0 <= 64 && deg1 <= 64) {
        prep(0, st0, en0, ad0);
        prep(1, st1, en1, ad1);
        __builtin_amdgcn_wave_barrier();
        // dual-node interleaved chains, depth-1: 2 independent loads in flight per wave
        int cm = deg0 > deg1 ? deg0 : deg1;  // extra iters of shorter node add alpha=0
        int sA = s_sh[w][0][0], sB = s_sh[w][1][0];
        f32x4 aA = *(const f32x4*)al_sh[w][0][0];
        f32x4 aB = *(const f32x4*)al_sh[w][1][0];
        u32 xA = *(const u32*)(XbfR + sA * 128 + lane * 2);
        u32 xB = *(const u32*)(XbfR + sB * 128 + lane * 2);
        for (int i = 0; i < cm; i++) {
            int sA2 = s_sh[w][0][i + 1], sB2 = s_sh[w][1][i + 1];  // sentinel covers i+1<=64
            f32x4 aA2 = *(const f32x4*)al_sh[w][0][i + 1];
            f32x4 aB2 = *(const f32x4*)al_sh[w][1][i + 1];
            u32 xA2 = *(const u32*)(XbfR + sA2 * 128 + lane * 2);
            u32 xB2 = *(const u32*)(XbfR + sB2 * 128 + lane * 2);
            acc00 += aA * __uint_as_float(xA << 16);
            acc01 += aA * __uint_as_float(xA & 0xffff0000u);
            acc10 += aB * __uint_as_float(xB << 16);
            acc11 += aB * __uint_as_float(xB & 0xffff0000u);
            xA = xA2; aA = aA2;
            xB = xB2; aB = aB2;
        }
        u16* a0 = As + (w * 2) * 520 + lane * 2;
        u16* a1 = As + (w * 2 + 1) * 520 + lane * 2;
        for (int h = 0; h < 4; h++) {
            *(u32*)(a0 + h * 128) = pack2bf(acc00[h], acc01[h]);
            *(u32*)(a1 + h * 128) = pack2bf(acc10[h], acc11[h]);
        }
    } else {
        gen(0, st0, en0, ad0, w * 2);
        gen(1, st1, en1, ad1, w * 2 + 1);
    }
    __syncthreads();  // As ready; s_sh/al_sh dead beyond this point (aggbuf aliases them)

    // ---------------- MFMA phase: wave w -> head w>>1, col-half w&1; M=16 (all real) --------
    const int h = w >> 1, colhalf = w & 1;
    const int lrow = lane & 15, quad = lane >> 4;
    f32x4 macc[4] = {};
    for (int k4 = 0; k4 < 4; k4++) {
        bf16x8 a = *(const bf16x8*)(As + lrow * 520 + h * 128 + k4 * 32 + quad * 8);
        for (int ni = 0; ni < 4; ni++) {
            bf16x8 bfrag = *(const bf16x8*)(Wt + (h * 128 + colhalf * 64 + ni * 16 + lrow) * 128 +
                                            k4 * 32 + quad * 8);
            macc[ni] = __builtin_amdgcn_mfma_f32_16x16x32_bf16(a, bfrag, macc[ni], 0, 0, 0);
        }
    }
    // bias + elu, 4-consecutive-col mean via shfl (head-major flat: out ch i = mean flat[4i..4i+3])
    for (int ni = 0; ni < 4; ni++) {
        float bv = bias[h * 128 + colhalf * 64 + ni * 16 + lrow];
        for (int r = 0; r < 4; r++) {
            float v = macc[ni][r] + bv;
            v = v > 0.f ? v : __expf(v) - 1.f;
            v += __shfl_xor(v, 1);
            v += __shfl_xor(v, 2);
            if ((lrow & 3) == 0) {
                int row = quad * 4 + r;
                int cO = h * 32 + colhalf * 16 + ni * 4 + (lrow >> 2);
                aggbuf[row * 132 + cO] = 0.25f * v;
            }
        }
    }
    __syncthreads();

    // ---------------- recurrence (coalesced) ----------------
    {
        int c2 = t & 127, rg = t >> 7;  // 512 threads: 128 ch x 4 row-groups
        for (int rr = 0; rr < 4; rr++) {
            int row = rg * 4 + rr;
            float agg = aggbuf[row * 132 + c2];
            int node = r0 + row;
            int xo = node * LSTRIDE + layer * 128 + c2;
            float xp = Xall[xo];
            Xall[xo + 128] = agg;
            Yall[xo + 128] = agg - xp;
            XbfW[node * 128 + c2] = f2bf(agg);
        }
    }
    if (mode == 0) {
        // next-layer logits: wave w rows 2w, 2w+1
        f32x4 vs0 = *(const f32x4*)(Vs + lane * 4), vs1 = *(const f32x4*)(Vs + (64 + lane) * 4);
        f32x4 vd0 = *(const f32x4*)(Vd + lane * 4), vd1 = *(const f32x4*)(Vd + (64 + lane) * 4);
        for (int rr = 0; rr < 2; rr++) {
            int row = w * 2 + rr;
            float x0 = aggbuf[row * 132 + lane], x1 = aggbuf[row * 132 + 64 + lane];
            f32x4 ps = x0 * vs0 + x1 * vs1;
            f32x4 pd = x0 * vd0 + x1 * vd1;
            for (int off = 32; off; off >>= 1)
                for (int c2 = 0; c2 < 4; c2++) {
                    ps[c2] += __shfl_xor(ps[c2], off);
                    pd[c2] += __shfl_xor(pd[c2], off);
                }
            if (lane == 0) {
                int node = r0 + row;
                *(f32x4*)(a_s_nxt + node * 4) = ps;
                *(f32x4*)(a_d_nxt + node * 4) = pd;
            }
        }
    } else {
        // fused readout: out[node][40] = agg @ Wr^T + br; lane-per-class
        if (lane < NCLASS) {
            for (int rr = 0; rr < 2; rr++) {
                int row = w * 2 + rr;
                float accv = 0.f;
                for (int kc = 0; kc < 32; kc++) {
                    f32x4 wv = *(const f32x4*)(Wr + lane * 128 + kc * 4);
                    f32x4 xv = *(const f32x4*)&aggbuf[row * 132 + kc * 4];
                    accv += wv[0] * xv[0] + wv[1] * xv[1] + wv[2] * xv[2] + wv[3] * xv[3];
                }
                outp[(r0 + row) * NCLASS + lane] = accv + br[lane];
            }
        }
    }
}

extern "C" void kernel_launch(void* const* d_in, const int* in_sizes, int n_in,
                              void* d_out, int out_size, void* d_ws, size_t ws_size,
                              hipStream_t stream) {
    const float* x = (const float*)d_in[0];
    const int* src = (const int*)d_in[1];
    const int* dst = (const int*)d_in[2];
    const float* W = (const float*)d_in[3];
    const float* att_s = (const float*)d_in[4];
    const float* att_d = (const float*)d_in[5];
    const float* bias = (const float*)d_in[6];
    const float* Wr = (const float*)d_in[7];
    const float* br = (const float*)d_in[8];

    float* out = (float*)d_out;
    float* Xall = out + (size_t)N_NODES * NCLASS;
    float* Yall = Xall + (size_t)N_NODES * LSTRIDE;

    char* p = (char*)d_ws;
    auto alloc = [&](size_t bytes) -> char* {
        char* r = p;
        p += (bytes + 255) & ~(size_t)255;
        return r;
    };
    u16* XbfA = (u16*)alloc((size_t)N_NODES * 128 * 2);
    u16* XbfB = (u16*)alloc((size_t)N_NODES * 128 * 2);
    u16* Wt = (u16*)alloc(512 * 128 * 2);
    float* a_sA = (float*)alloc((size_t)N_NODES * 4 * 4);
    float* a_dA = (float*)alloc((size_t)N_NODES * 4 * 4);
    float* a_sB = (float*)alloc((size_t)N_NODES * 4 * 4);
    float* a_dB = (float*)alloc((size_t)N_NODES * 4 * 4);
    float* Vs = (float*)alloc(128 * 4 * 4);
    float* Vd = (float*)alloc(128 * 4 * 4);
    int* indptr = (int*)alloc((N_NODES + 1) * 4);
    int* cursor = (int*)alloc(N_NODES * 4);
    int* counts = (int*)alloc(N_NODES * 4);
    int* esrc = (int*)alloc((size_t)(NE + N_NODES) * 4);

    hipMemsetAsync(counts, 0, N_NODES * sizeof(int), stream);
    k_pre1<<<P1_INIT + P1_TRANS + P1_FOLD + P1_COUNT, 256, 0, stream>>>(
        x, dst, W, att_s, att_d, XbfA, Xall, Yall, Wt, Vs, Vd, counts);
    k_pre2<<<1251, 1024, 0, stream>>>(counts, indptr, cursor, x, Vs, Vd, a_sA, a_dA);
    k_scatter<<<(NE + N_NODES + 255) / 256, 256, 0, stream>>>(src, dst, cursor, esrc);

    for (int layer = 0; layer < NLAYERS; layer++) {
        const float* as_r = (layer & 1) ? a_sB : a_sA;
        const float* ad_r = (layer & 1) ? a_dB : a_dA;
        float* as_w = (layer & 1) ? a_sA : a_sB;
        float* ad_w = (layer & 1) ? a_dA : a_dB;
        const u16* xr = (layer & 1) ? XbfB : XbfA;
        u16* xw = (layer & 1) ? XbfA : XbfB;
        k_layer<<<N_NODES / 16, 512, 0, stream>>>(indptr, esrc, as_r, ad_r, xr, Wt, bias,
                                                  Xall, Yall, xw, as_w, ad_w, Vs, Vd,
                                                  Wr, br, out, layer,
                                                  (layer + 1 < NLAYERS) ? 0 : 1);
    }
}

// Round 9
// 482.874 us; speedup vs baseline: 1.0856x; 1.0856x over previous
//
#include <hip/hip_runtime.h>

typedef unsigned short u16;
typedef unsigned int u32;

#define N_NODES 20000
#define NE 320000
#define NLAYERS 4
#define NCLASS 40
#define NEG_SLOPE 0.2f
#define LSTRIDE ((NLAYERS + 1) * 128)  // 640 floats per node in X_all/Y_all

typedef __bf16 bf16x8 __attribute__((ext_vector_type(8)));
typedef float f32x4 __attribute__((ext_vector_type(4)));

__device__ inline u16 f2bf(float f) {
    u32 u = __float_as_uint(f);
    return (u16)((u + 0x7fffu + ((u >> 16) & 1u)) >> 16);  // round-nearest-even
}
__device__ inline u32 pack2bf(float lo, float hi) {
    return (u32)f2bf(lo) | ((u32)f2bf(hi) << 16);
}

// ================= pre1: init + W-transpose + att-fold + degree-count (block-partitioned) ====
#define P1_INIT 10000
#define P1_TRANS 256
#define P1_FOLD 128
#define P1_COUNT 1250
__global__ __launch_bounds__(256) void k_pre1(
    const float* __restrict__ x, const int* __restrict__ dst,
    const float* __restrict__ W, const float* __restrict__ att_s,
    const float* __restrict__ att_d,
    u16* __restrict__ Xbf, float* __restrict__ Xall, float* __restrict__ Yall,
    u16* __restrict__ Wt, float* __restrict__ Vs, float* __restrict__ Vd,
    int* __restrict__ counts) {
    int b = blockIdx.x;
    if (b < P1_INIT) {
        int t = b * 256 + threadIdx.x;
        float v = x[t];
        Xbf[t] = f2bf(v);
        int n = t >> 7, c = t & 127;
        int ob = n * LSTRIDE + c;
        Xall[ob] = v;
        Yall[ob] = v;
    } else if (b < P1_INIT + P1_TRANS) {
        int t = (b - P1_INIT) * 256 + threadIdx.x;
        int k = t >> 9, col = t & 511;
        Wt[col * 128 + k] = f2bf(W[t]);
    } else if (b < P1_INIT + P1_TRANS + P1_FOLD) {
        int wid = ((b - P1_INIT - P1_TRANS) * 256 + threadIdx.x) >> 6;
        int lane = threadIdx.x & 63;
        int t = wid >> 2, hd = wid & 3;
        float w0 = W[t * 512 + hd * 128 + lane];
        float w1 = W[t * 512 + hd * 128 + 64 + lane];
        float s1 = w0 * att_s[hd * 128 + lane] + w1 * att_s[hd * 128 + 64 + lane];
        float s2 = w0 * att_d[hd * 128 + lane] + w1 * att_d[hd * 128 + 64 + lane];
        for (int off = 32; off; off >>= 1) {
            s1 += __shfl_xor(s1, off);
            s2 += __shfl_xor(s2, off);
        }
        if (lane == 0) {
            Vs[t * 4 + hd] = s1;
            Vd[t * 4 + hd] = s2;
        }
    } else {
        int t = (b - P1_INIT - P1_TRANS - P1_FOLD) * 256 + threadIdx.x;
        atomicAdd(&counts[dst[t]], 1);
    }
}

// ================= pre2: block 0 = CSR scan (+1 self loop); blocks 1.. = layer-0 logits ====
__global__ __launch_bounds__(1024) void k_pre2(
    const int* __restrict__ counts, int* __restrict__ indptr, int* __restrict__ cursor,
    const float* __restrict__ x, const float* __restrict__ Vs, const float* __restrict__ Vd,
    float* __restrict__ a_s, float* __restrict__ a_d) {
    if (blockIdx.x == 0) {
        __shared__ int part[1024];
        int t = threadIdx.x;
        const int CH = 20;
        int c0 = t * CH;
        int s = 0;
        for (int i = 0; i < CH; i++) {
            int idx = c0 + i;
            if (idx < N_NODES) s += counts[idx] + 1;
        }
        part[t] = s;
        __syncthreads();
        for (int off = 1; off < 1024; off <<= 1) {
            int v = 0;
            if (t >= off) v = part[t - off];
            __syncthreads();
            if (t >= off) part[t] += v;
            __syncthreads();
        }
        int ex = (t == 0) ? 0 : part[t - 1];
        for (int i = 0; i < CH; i++) {
            int idx = c0 + i;
            if (idx < N_NODES) {
                indptr[idx] = ex;
                cursor[idx] = ex;
                ex += counts[idx] + 1;
            }
        }
        if (t == 1023) indptr[N_NODES] = part[1023];
    } else {
        int wave = threadIdx.x >> 6, lane = threadIdx.x & 63;
        int n = (blockIdx.x - 1) * 16 + wave;
        const float* Xr = x + n * 128;
        float x0 = Xr[lane], x1 = Xr[64 + lane];
        f32x4 vs0 = *(const f32x4*)(Vs + lane * 4), vs1 = *(const f32x4*)(Vs + (64 + lane) * 4);
        f32x4 vd0 = *(const f32x4*)(Vd + lane * 4), vd1 = *(const f32x4*)(Vd + (64 + lane) * 4);
        f32x4 ps = x0 * vs0 + x1 * vs1;
        f32x4 pd = x0 * vd0 + x1 * vd1;
        for (int off = 32; off; off >>= 1)
            for (int c = 0; c < 4; c++) {
                ps[c] += __shfl_xor(ps[c], off);
                pd[c] += __shfl_xor(pd[c], off);
            }
        if (lane == 0) {
            *(f32x4*)(a_s + n * 4) = ps;
            *(f32x4*)(a_d + n * 4) = pd;
        }
    }
}

// ================= scatter: CSR fill (edges + self loops) ==================
__global__ void k_scatter(const int* __restrict__ src, const int* __restrict__ dst,
                          int* __restrict__ cursor, int* __restrict__ esrc) {
    int t = blockIdx.x * 256 + threadIdx.x;
    if (t >= NE + N_NODES) return;
    int s, d;
    if (t < NE) { s = src[t]; d = dst[t]; }
    else { s = d = t - NE; }
    int pos = atomicAdd(&cursor[d], 1);
    esrc[pos] = s;
}

// ================= fused layer — ROUND-4 BODY VERBATIM, LDS union only ==================
// block = 512 threads (8 waves), 16 nodes; grid 1250 exact.
// VGPR map (measured): forced-32 -> spills (R7, 120us); natural-64 (R4, 65us, BEST);
// 84 (R8 readout fusion) and 108 (R6 depth-2) -> occupancy cliff. This kernel must stay
// at the R4 body so the allocator lands on 64. Only change vs R4: gather buffers union'd
// with aggbuf via a proper union type (compile-time offsets, no casts) -> LDS 46.2->37.8KB
// -> 4 blocks/CU instead of 3 at 64 VGPR.
struct GatherBufs {
    int s_sh[8][2][66];
    float al_sh[8][2][66][4];
};
union LayerSmem {
    GatherBufs g;            // gather phase (dead after the As-ready __syncthreads)
    float aggbuf[16 * 130];  // epilogue phase
};
__global__ __launch_bounds__(512) void k_layer(
    const int* __restrict__ indptr, const int* __restrict__ esrc,
    const float* __restrict__ a_s, const float* __restrict__ a_d,
    const u16* __restrict__ XbfR, const u16* __restrict__ Wt,
    const float* __restrict__ bias,
    float* __restrict__ Xall, float* __restrict__ Yall, u16* __restrict__ XbfW,
    float* __restrict__ a_s_nxt, float* __restrict__ a_d_nxt,
    const float* __restrict__ Vs, const float* __restrict__ Vd,
    int layer, int do_logits) {
    __shared__ LayerSmem sm;
    __shared__ alignas(16) u16 As[16 * 520];  // 16 node-rows x 512 (head-major) + pad
    const int t = threadIdx.x;
    const int r0 = blockIdx.x * 16;
    const int w = t >> 6, lane = t & 63;

    f32x4 acc00 = {0.f, 0.f, 0.f, 0.f}, acc01 = {0.f, 0.f, 0.f, 0.f};  // node0: ch 2l, 2l+1
    f32x4 acc10 = {0.f, 0.f, 0.f, 0.f}, acc11 = {0.f, 0.f, 0.f, 0.f};  // node1
    int d0 = r0 + w * 2;
    int st0 = indptr[d0], en0 = indptr[d0 + 1], en1 = indptr[d0 + 2];
    int st1 = en0;
    int deg0 = en0 - st0, deg1 = en1 - st1;
    f32x4 ad0 = *(const f32x4*)(a_d + d0 * 4);
    f32x4 ad1 = *(const f32x4*)(a_d + d0 * 4 + 4);

    // softmax for <=64-edge node: e kept in registers, (s, alpha[4]) to per-wave LDS
    auto prep = [&](int nd, int st, int en, f32x4 ad) {
        int j = st + lane;
        int s = 0;
        f32x4 e = {-1e30f, -1e30f, -1e30f, -1e30f};
        if (j < en) {
            s = esrc[j];
            f32x4 as = *(const f32x4*)(a_s + s * 4);
            for (int c = 0; c < 4; c++) {
                float v = as[c] + ad[c];
                e[c] = v > 0.f ? v : NEG_SLOPE * v;
            }
        }
        f32x4 mx = e;
        for (int off = 32; off; off >>= 1)
            for (int c = 0; c < 4; c++) mx[c] = fmaxf(mx[c], __shfl_xor(mx[c], off));
        f32x4 p;
        for (int c = 0; c < 4; c++) p[c] = __expf(e[c] - mx[c]);  // invalid lanes -> 0
        f32x4 den = p;
        for (int off = 32; off; off >>= 1)
            for (int c = 0; c < 4; c++) den[c] += __shfl_xor(den[c], off);
        f32x4 alpha;
        for (int c = 0; c < 4; c++) alpha[c] = p[c] * (1.f / den[c]);
        sm.g.s_sh[w][nd][lane] = s;
        *(f32x4*)sm.g.al_sh[w][nd][lane] = alpha;
        if (lane == 63) {
            sm.g.s_sh[w][nd][64] = 0;
            f32x4 z = {0.f, 0.f, 0.f, 0.f};
            *(f32x4*)sm.g.al_sh[w][nd][64] = z;
        }
    };
    // single-node pipelined aggregate over an LDS chunk
    auto chunk1 = [&](int nd, int cnt, f32x4& aL, f32x4& aH) {
        int sc = sm.g.s_sh[w][nd][0];
        f32x4 al = *(const f32x4*)sm.g.al_sh[w][nd][0];
        u32 xv = *(const u32*)(XbfR + sc * 128 + lane * 2);
        for (int i = 0; i < cnt; i++) {
            int sn = sm.g.s_sh[w][nd][i + 1];
            f32x4 an = *(const f32x4*)sm.g.al_sh[w][nd][i + 1];
            u32 xn = *(const u32*)(XbfR + sn * 128 + lane * 2);
            aL += al * __uint_as_float(xv << 16);
            aH += al * __uint_as_float(xv & 0xffff0000u);
            xv = xn;
            al = an;
        }
    };
    // general path (deg > 64): strided 3-pass softmax, chunked aggregate
    auto gen = [&](int nd, int st, int en, f32x4 ad, f32x4& aL, f32x4& aH) {
        f32x4 mx = {-1e30f, -1e30f, -1e30f, -1e30f};
        for (int j = st + lane; j < en; j += 64) {
            int s = esrc[j];
            f32x4 e = *(const f32x4*)(a_s + s * 4) + ad;
            for (int c = 0; c < 4; c++) {
                float v = e[c];
                v = v > 0.f ? v : NEG_SLOPE * v;
                mx[c] = fmaxf(mx[c], v);
            }
        }
        for (int off = 32; off; off >>= 1)
            for (int c = 0; c < 4; c++) mx[c] = fmaxf(mx[c], __shfl_xor(mx[c], off));
        f32x4 den = {0.f, 0.f, 0.f, 0.f};
        for (int j = st + lane; j < en; j += 64) {
            int s = esrc[j];
            f32x4 e = *(const f32x4*)(a_s + s * 4) + ad;
            for (int c = 0; c < 4; c++) {
                float v = e[c];
                v = v > 0.f ? v : NEG_SLOPE * v;
                den[c] += __expf(v - mx[c]);
            }
        }
        for (int off = 32; off; off >>= 1)
            for (int c = 0; c < 4; c++) den[c] += __shfl_xor(den[c], off);
        f32x4 rd;
        for (int c = 0; c < 4; c++) rd[c] = 1.f / den[c];
        for (int base = st; base < en; base += 64) {
            int cnt = min(64, en - base);
            int jj = base + lane;
            int s = 0;
            f32x4 alpha = {0.f, 0.f, 0.f, 0.f};
            if (jj < en) {
                s = esrc[jj];
                f32x4 e = *(const f32x4*)(a_s + s * 4) + ad;
                for (int c = 0; c < 4; c++) {
                    float v = e[c];
                    v = v > 0.f ? v : NEG_SLOPE * v;
                    alpha[c] = __expf(v - mx[c]) * rd[c];
                }
            }
            sm.g.s_sh[w][nd][lane] = s;
            *(f32x4*)sm.g.al_sh[w][nd][lane] = alpha;
            if (lane == 63) {
                sm.g.s_sh[w][nd][64] = 0;
                f32x4 z = {0.f, 0.f, 0.f, 0.f};
                *(f32x4*)sm.g.al_sh[w][nd][64] = z;
            }
            __builtin_amdgcn_wave_barrier();
            chunk1(nd, cnt, aL, aH);
            __builtin_amdgcn_wave_barrier();
        }
    };

    if (deg0 <= 64 && deg1 <= 64) {
        prep(0, st0, en0, ad0);
        prep(1, st1, en1, ad1);
        __builtin_amdgcn_wave_barrier();
        // interleaved dual-node pipeline: 2 independent load chains in flight
        int cm = deg0 > deg1 ? deg0 : deg1;  // extra iters of shorter node add alpha=0
        int sA = sm.g.s_sh[w][0][0], sB = sm.g.s_sh[w][1][0];
        f32x4 aA = *(const f32x4*)sm.g.al_sh[w][0][0];
        f32x4 aB = *(const f32x4*)sm.g.al_sh[w][1][0];
        u32 xA = *(const u32*)(XbfR + sA * 128 + lane * 2);
        u32 xB = *(const u32*)(XbfR + sB * 128 + lane * 2);
        for (int i = 0; i < cm; i++) {
            int sA2 = sm.g.s_sh[w][0][i + 1], sB2 = sm.g.s_sh[w][1][i + 1];
            f32x4 aA2 = *(const f32x4*)sm.g.al_sh[w][0][i + 1];
            f32x4 aB2 = *(const f32x4*)sm.g.al_sh[w][1][i + 1];
            u32 xA2 = *(const u32*)(XbfR + sA2 * 128 + lane * 2);
            u32 xB2 = *(const u32*)(XbfR + sB2 * 128 + lane * 2);
            acc00 += aA * __uint_as_float(xA << 16);
            acc01 += aA * __uint_as_float(xA & 0xffff0000u);
            acc10 += aB * __uint_as_float(xB << 16);
            acc11 += aB * __uint_as_float(xB & 0xffff0000u);
            xA = xA2; aA = aA2; xB = xB2; aB = aB2;
        }
    } else {
        gen(0, st0, en0, ad0, acc00, acc01);
        gen(1, st1, en1, ad1, acc10, acc11);
    }

    // write aggregated rows into As (head-major bf16)
    {
        u16* a0 = As + (w * 2) * 520 + lane * 2;
        u16* a1 = As + (w * 2 + 1) * 520 + lane * 2;
        for (int h = 0; h < 4; h++) {
            *(u32*)(a0 + h * 128) = pack2bf(acc00[h], acc01[h]);
            *(u32*)(a1 + h * 128) = pack2bf(acc10[h], acc11[h]);
        }
    }
    __syncthreads();  // As ready; gather bufs dead -> aggbuf may now alias them

    // ---------------- MFMA phase: wave w -> head w>>1, col-half w&1 ----------------
    const int h = w >> 1, colhalf = w & 1;
    const int lrow = lane & 15, quad = lane >> 4;
    f32x4 macc[4] = {};
    for (int k4 = 0; k4 < 4; k4++) {
        bf16x8 a = *(const bf16x8*)(As + lrow * 520 + h * 128 + k4 * 32 + quad * 8);
        for (int ni = 0; ni < 4; ni++) {
            bf16x8 bfrag = *(const bf16x8*)(Wt + (h * 128 + colhalf * 64 + ni * 16 + lrow) * 128 +
                                            k4 * 32 + quad * 8);
            macc[ni] = __builtin_amdgcn_mfma_f32_16x16x32_bf16(a, bfrag, macc[ni], 0, 0, 0);
        }
    }
    // bias + elu per element, then 4-consecutive-mean via 4-lane shuffle sum.
    for (int ni = 0; ni < 4; ni++) {
        float bv = bias[h * 128 + colhalf * 64 + ni * 16 + lrow];
        for (int r = 0; r < 4; r++) {
            float v = macc[ni][r] + bv;
            v = v > 0.f ? v : __expf(v) - 1.f;
            v += __shfl_xor(v, 1);
            v += __shfl_xor(v, 2);
            if ((lrow & 3) == 0) {
                int row = quad * 4 + r;
                int cO = h * 32 + colhalf * 16 + ni * 4 + (lrow >> 2);
                sm.aggbuf[row * 130 + cO] = 0.25f * v;
            }
        }
    }
    __syncthreads();

    // ---------------- epilogue: recurrence (coalesced) ----------------
    {
        int c = t & 127, rg = t >> 7;  // 512 threads: 128 ch x 4 row-groups
        for (int rr = 0; rr < 4; rr++) {
            int row = rg * 4 + rr;
            float agg = sm.aggbuf[row * 130 + c];
            int node = r0 + row;
            int xo = node * LSTRIDE + layer * 128 + c;
            float xp = Xall[xo];
            Xall[xo + 128] = agg;        // X2 = agg
            Yall[xo + 128] = agg - xp;   // Y2 = agg - X_prev
            XbfW[node * 128 + c] = f2bf(agg);
        }
    }
    // ---------------- next-layer logits ----------------
    if (do_logits) {
        f32x4 vs0 = *(const f32x4*)(Vs + lane * 4), vs1 = *(const f32x4*)(Vs + (64 + lane) * 4);
        f32x4 vd0 = *(const f32x4*)(Vd + lane * 4), vd1 = *(const f32x4*)(Vd + (64 + lane) * 4);
        for (int rr = 0; rr < 2; rr++) {
            int row = w * 2 + rr;
            float x0 = sm.aggbuf[row * 130 + lane], x1 = sm.aggbuf[row * 130 + 64 + lane];
            f32x4 ps = x0 * vs0 + x1 * vs1;
            f32x4 pd = x0 * vd0 + x1 * vd1;
            for (int off = 32; off; off >>= 1)
                for (int c2 = 0; c2 < 4; c2++) {
                    ps[c2] += __shfl_xor(ps[c2], off);
                    pd[c2] += __shfl_xor(pd[c2], off);
                }
            if (lane == 0) {
                int node = r0 + row;
                *(f32x4*)(a_s_nxt + node * 4) = ps;
                *(f32x4*)(a_d_nxt + node * 4) = pd;
            }
        }
    }
}

// ================= readout: out[N][40] = X_final @ Wr^T + br ==================
__global__ __launch_bounds__(256) void k_out(const float* __restrict__ Xall,
                                             const float* __restrict__ Wr,
                                             const float* __restrict__ br,
                                             float* __restrict__ out) {
    __shared__ float Xs[4][128];
    int wave = threadIdx.x >> 6, lane = threadIdx.x & 63;
    int n = blockIdx.x * 4 + wave;  // grid exact: 5000 blocks
    const float* Xr = Xall + n * LSTRIDE + NLAYERS * 128;
    Xs[wave][lane] = Xr[lane];
    Xs[wave][64 + lane] = Xr[64 + lane];
    __syncthreads();
    if (lane < NCLASS) {
        float acc = 0.f;
        for (int kc = 0; kc < 32; kc++) {
            f32x4 wv = *(const f32x4*)(Wr + lane * 128 + kc * 4);
            for (int q = 0; q < 4; q++) acc += Xs[wave][kc * 4 + q] * wv[q];
        }
        out[n * NCLASS + lane] = acc + br[lane];
    }
}

extern "C" void kernel_launch(void* const* d_in, const int* in_sizes, int n_in,
                              void* d_out, int out_size, void* d_ws, size_t ws_size,
                              hipStream_t stream) {
    const float* x = (const float*)d_in[0];
    const int* src = (const int*)d_in[1];
    const int* dst = (const int*)d_in[2];
    const float* W = (const float*)d_in[3];
    const float* att_s = (const float*)d_in[4];
    const float* att_d = (const float*)d_in[5];
    const float* bias = (const float*)d_in[6];
    const float* Wr = (const float*)d_in[7];
    const float* br = (const float*)d_in[8];

    float* out = (float*)d_out;
    float* Xall = out + (size_t)N_NODES * NCLASS;
    float* Yall = Xall + (size_t)N_NODES * LSTRIDE;

    char* p = (char*)d_ws;
    auto alloc = [&](size_t bytes) -> char* {
        char* r = p;
        p += (bytes + 255) & ~(size_t)255;
        return r;
    };
    u16* XbfA = (u16*)alloc((size_t)N_NODES * 128 * 2);
    u16* XbfB = (u16*)alloc((size_t)N_NODES * 128 * 2);
    u16* Wt = (u16*)alloc(512 * 128 * 2);
    float* a_sA = (float*)alloc((size_t)N_NODES * 4 * 4);
    float* a_dA = (float*)alloc((size_t)N_NODES * 4 * 4);
    float* a_sB = (float*)alloc((size_t)N_NODES * 4 * 4);
    float* a_dB = (float*)alloc((size_t)N_NODES * 4 * 4);
    float* Vs = (float*)alloc(128 * 4 * 4);
    float* Vd = (float*)alloc(128 * 4 * 4);
    int* indptr = (int*)alloc((N_NODES + 1) * 4);
    int* cursor = (int*)alloc(N_NODES * 4);
    int* counts = (int*)alloc(N_NODES * 4);
    int* esrc = (int*)alloc((size_t)(NE + N_NODES) * 4);

    hipMemsetAsync(counts, 0, N_NODES * sizeof(int), stream);
    k_pre1<<<P1_INIT + P1_TRANS + P1_FOLD + P1_COUNT, 256, 0, stream>>>(
        x, dst, W, att_s, att_d, XbfA, Xall, Yall, Wt, Vs, Vd, counts);
    k_pre2<<<1251, 1024, 0, stream>>>(counts, indptr, cursor, x, Vs, Vd, a_sA, a_dA);
    k_scatter<<<(NE + N_NODES + 255) / 256, 256, 0, stream>>>(src, dst, cursor, esrc);

    for (int layer = 0; layer < NLAYERS; layer++) {
        const float* as_r = (layer & 1) ? a_sB : a_sA;
        const float* ad_r = (layer & 1) ? a_dB : a_dA;
        float* as_w = (layer & 1) ? a_sA : a_sB;
        float* ad_w = (layer & 1) ? a_dA : a_dB;
        const u16* xr = (layer & 1) ? XbfB : XbfA;
        u16* xw = (layer & 1) ? XbfA : XbfB;
        k_layer<<<N_NODES / 16, 512, 0, stream>>>(indptr, esrc, as_r, ad_r, xr, Wt, bias,
                                                  Xall, Yall, xw, as_w, ad_w, Vs, Vd, layer,
                                                  (layer + 1 < NLAYERS) ? 1 : 0);
    }
    k_out<<<N_NODES / 4, 256, 0, stream>>>(Xall, Wr, br, out);
}